// Round 6
// baseline (82.351 us; speedup 1.0000x reference)
//
#include <hip/hip_runtime.h>
#include <hip/hip_bf16.h>

typedef short short8 __attribute__((ext_vector_type(8)));
typedef float f32x4 __attribute__((ext_vector_type(4)));
typedef unsigned short ushort_t;

#define TOKENS 4096
#define IN_F   2048
#define OUT_F  2048
#define NBLK   2048
#define NROWB  64
#define ROWCAP 2064
#define NSLOT  5

#define MFMA_BF16 __builtin_amdgcn_mfma_f32_16x16x32_bf16

__device__ __forceinline__ ushort_t f2bf(float f) {
    unsigned int u = __float_as_uint(f);
    u += 0x7FFFu + ((u >> 16) & 1u);   // RTNE
    return (ushort_t)(u >> 16);
}

__device__ __forceinline__ void gll16(const void* g, void* l) {
    __builtin_amdgcn_global_load_lds(
        (const __attribute__((address_space(1))) unsigned int*)g,
        (__attribute__((address_space(3))) unsigned int*)l, 16, 0, 0);
}

// ---------------- prep: x relayout+cvt | w cvt | bucketize + col-sort ----------------
// xc layout: tile tc = cb*64 + t64 (4 KB each): [tok_in 0..63][col 0..31] bf16.
__global__ __launch_bounds__(256)
void prep_kernel(const float* __restrict__ x, const float* __restrict__ wblk,
                 const int* __restrict__ brows, const int* __restrict__ bcols,
                 ushort_t* __restrict__ xc, ushort_t* __restrict__ wb,
                 int* __restrict__ bucket, int* __restrict__ bcnt) {
    __shared__ int tmp[4][64];
    const int bid = blockIdx.x;
    const int tid = threadIdx.x;

    if (bid < 4096) {
        // x: 1,048,576 16B-chunks
        int ci  = bid * 256 + tid;
        int s   = ci & 255;
        int tc  = ci >> 8;
        int cb  = tc >> 6;
        int t64 = tc & 63;
        int tok = t64 * 64 + (s >> 2);
        int col = cb * 32 + (s & 3) * 8;
        const float* src = x + (size_t)tok * IN_F + col;
        float4 v0 = *reinterpret_cast<const float4*>(src);
        float4 v1 = *reinterpret_cast<const float4*>(src + 4);
        short8 o;
        o[0] = f2bf(v0.x); o[1] = f2bf(v0.y); o[2] = f2bf(v0.z); o[3] = f2bf(v0.w);
        o[4] = f2bf(v1.x); o[5] = f2bf(v1.y); o[6] = f2bf(v1.z); o[7] = f2bf(v1.w);
        reinterpret_cast<short8*>(xc)[ci] = o;
    } else if (bid < 5120) {
        int i = (bid - 4096) * 256 + tid;
        const float* src = wblk + (size_t)i * 8;
        float4 v0 = *reinterpret_cast<const float4*>(src);
        float4 v1 = *reinterpret_cast<const float4*>(src + 4);
        short8 o;
        o[0] = f2bf(v0.x); o[1] = f2bf(v0.y); o[2] = f2bf(v0.z); o[3] = f2bf(v0.w);
        o[4] = f2bf(v1.x); o[5] = f2bf(v1.y); o[6] = f2bf(v1.z); o[7] = f2bf(v1.w);
        reinterpret_cast<short8*>(wb)[i] = o;
    } else {
        // bucketize + sort-by-col: 16 blocks x 4 waves = 64 rows
        const int wv   = tid >> 6;
        const int lane = tid & 63;
        const int r    = (bid - 5120) * 4 + wv;
        const int per  = NBLK / 64;
        const int base = lane * per;
        int cnt = 0;
        for (int k = 0; k < per; ++k) cnt += (brows[base + k] == r) ? 1 : 0;
        int sum = cnt;
        for (int d = 1; d < 64; d <<= 1) {
            int v = __shfl_up(sum, d, 64);
            if (lane >= d) sum += v;
        }
        int off = sum - cnt;
        for (int k = 0; k < per; ++k) {
            int n = base + k;
            if (brows[n] == r) tmp[wv][off++] = (n << 6) | bcols[n];
        }
        int total = __shfl(sum, 63, 64);
        __syncthreads();
        // counting-rank sort by (col, index) via 64-round shuffle (total <= 64 for this data)
        int e   = (lane < total) ? tmp[wv][lane] : 0x7FFFFFFF;
        int key = (lane < total) ? (((e & 63) << 6) | lane) : 0x7FFFFFFF;
        int rank = 0;
        for (int j = 0; j < 64; ++j) {
            int kj = __shfl(key, j, 64);
            rank += (kj < key) ? 1 : 0;
        }
        if (lane < total) bucket[r * ROWCAP + rank] = e;
        if (lane == 0)    bcnt[r] = total;
    }
}

// ---------------- main kernel: LDS-shared A-panels, phased over colblocks ----------------
// 256 WGs x 512 thr (8 waves). WG(chunk=wg&7, slab=wg>>3): rows chunk*8..+8 (one per
// wave), tokens slab*128..+128. 16 phases of 4 colblocks; panels double-buffered in
// LDS via global_load_lds; per-row col-sorted block list with 5 B-prefetch slots.
__global__ __launch_bounds__(512, 2)
void bsl_mfma_kernel(const ushort_t* __restrict__ xc,
                     const ushort_t* __restrict__ wb,
                     const int* __restrict__ bucket,
                     const int* __restrict__ bcnt,
                     float* __restrict__ out) {
    __shared__ ushort_t panels[2][4][4096];   // 2 buf x 4 cb x 8 KB = 64 KB

    const int wg    = blockIdx.x;         // [0,256)
    const int chunk = wg & 7;             // XCD residue -> row group
    const int slab  = wg >> 3;            // [0,32) 128-token slab
    const int tid   = threadIdx.x;
    const int wv    = tid >> 6;           // [0,8)
    const int lane  = tid & 63;
    const int l15   = lane & 15;
    const int hi    = lane >> 4;
    const int r     = chunk * 8 + wv;     // this wave's output row-block
    const int tok0  = slab * 128;

    const int  cnt = bcnt[r];
    const int* bl  = bucket + r * ROWCAP;

    f32x4 acc[8][2];
    #pragma unroll
    for (int m = 0; m < 8; ++m)
        #pragma unroll
        for (int n = 0; n < 2; ++n)
            acc[m][n] = (f32x4){0.f, 0.f, 0.f, 0.f};

    const ushort_t* wbase = wb + l15 * 32 + hi * 8;   // + n*1024 (+512 for frag1)

    auto LDB = [&](int n, short8& b0, short8& b1) {
        const ushort_t* wp = wbase + (size_t)n * 1024;
        b0 = *reinterpret_cast<const short8*>(wp);
        b1 = *reinterpret_cast<const short8*>(wp + 512);
    };
    // stage phase ph (cbs ph*4..+4) into buffer b: 4 x 1KB global_load_lds per wave
    auto STAGE = [&](int ph, int b) {
        #pragma unroll
        for (int i = 0; i < 4; ++i) {
            int cb = ph * 4 + i;
            const ushort_t* src = xc + (size_t)(cb * 64 + 2 * slab) * 2048 + wv * 512 + lane * 8;
            gll16(src, &panels[b][i][wv * 512]);
        }
    };
    auto AFRAG = [&](int b, int cbsub, short8 (&a)[8]) {
        #pragma unroll
        for (int m = 0; m < 8; ++m) {
            const ushort_t* pp = &panels[b][cbsub][(m >> 2) * 2048 + ((m & 3) * 16 + l15) * 32 + hi * 8];
            a[m] = *reinterpret_cast<const short8*>(pp);
        }
    };
    auto MMA = [&](short8 (&a)[8], short8 b0, short8 b1) {
        #pragma unroll
        for (int m = 0; m < 8; ++m) {
            acc[m][0] = MFMA_BF16(a[m], b0, acc[m][0], 0, 0, 0);
            acc[m][1] = MFMA_BF16(a[m], b1, acc[m][1], 0, 0, 0);
        }
    };

    int    kc = 0, kn = 0, jP = 0;
    int    scol[NSLOT], ncol[NSLOT];
    short8 sb0[NSLOT], sb1[NSLOT], nb0[NSLOT], nb1[NSLOT];
    #pragma unroll
    for (int i = 0; i < NSLOT; ++i) { scol[i] = 0; ncol[i] = 0; }

    // prologue: stage phase 0, prefetch window 0
    STAGE(0, 0);
    #pragma unroll
    for (int i = 0; i < NSLOT; ++i) {
        if (jP < cnt) {
            int e = __builtin_amdgcn_readfirstlane(bl[jP]);
            int c = e & 63;
            if (c < 4) { scol[i] = c; LDB(e >> 6, sb0[i], sb1[i]); jP++; kc = i + 1; }
        }
    }
    asm volatile("s_waitcnt vmcnt(0)" ::: "memory");
    __builtin_amdgcn_s_barrier();

    for (int p = 0; p < 16; ++p) {
        const int cur = p & 1, nxt = cur ^ 1;
        const int cb0 = p * 4;
        if (p < 15) STAGE(p + 1, nxt);

        // compute current window from slots
        __builtin_amdgcn_s_setprio(1);
        #pragma unroll
        for (int i = 0; i < NSLOT; ++i) {
            if (i < kc) {
                short8 a[8];
                AFRAG(cur, scol[i] - cb0, a);
                MMA(a, sb0[i], sb1[i]);
            }
        }
        __builtin_amdgcn_s_setprio(0);
        // overflow entries of this window (rare; >NSLOT in a 4-cb window)
        while (jP < cnt) {
            int e = __builtin_amdgcn_readfirstlane(bl[jP]);
            int c = e & 63;
            if (c >= cb0 + 4) break;
            short8 ob0, ob1, a[8];
            LDB(e >> 6, ob0, ob1);
            AFRAG(cur, c - cb0, a);
            MMA(a, ob0, ob1);
            jP++;
        }
        // prefetch next window's B into spare slots
        kn = 0;
        if (p < 15) {
            const int lim = cb0 + 8;
            #pragma unroll
            for (int i = 0; i < NSLOT; ++i) {
                if (jP < cnt) {
                    int e = __builtin_amdgcn_readfirstlane(bl[jP]);
                    int c = e & 63;
                    if (c < lim) { ncol[i] = c; LDB(e >> 6, nb0[i], nb1[i]); jP++; kn = i + 1; }
                }
            }
        }
        asm volatile("s_waitcnt vmcnt(0)" ::: "memory");
        __builtin_amdgcn_s_barrier();
        kc = kn;
        #pragma unroll
        for (int i = 0; i < NSLOT; ++i) { scol[i] = ncol[i]; sb0[i] = nb0[i]; sb1[i] = nb1[i]; }
    }

    // C/D layout: col = lane&15, row = (lane>>4)*4 + reg  [HW-verified]
    const int outc = r * 32 + l15;
    #pragma unroll
    for (int m = 0; m < 8; ++m) {
        #pragma unroll
        for (int ns = 0; ns < 2; ++ns) {
            #pragma unroll
            for (int reg = 0; reg < 4; ++reg) {
                int token = tok0 + m * 16 + hi * 4 + reg;
                out[(size_t)token * OUT_F + outc + ns * 16] = acc[m][ns][reg];
            }
        }
    }
}

extern "C" void kernel_launch(void* const* d_in, const int* in_sizes, int n_in,
                              void* d_out, int out_size, void* d_ws, size_t ws_size,
                              hipStream_t stream) {
    const float* x     = (const float*)d_in[0];
    const float* wblk  = (const float*)d_in[1];
    const int*   brows = (const int*)d_in[2];
    const int*   bcols = (const int*)d_in[3];
    float*       out   = (float*)d_out;

    char* ws = (char*)d_ws;
    ushort_t* xc     = (ushort_t*)(ws);                       // 16,777,216 B
    ushort_t* wb     = (ushort_t*)(ws + 16777216);            //  4,194,304 B
    int*      bucket = (int*)(ws + 20971520);                 //    528,384 B (64 x 2064)
    int*      bcnt   = (int*)(ws + 21499904);                 //        256 B

    // 4096 (x relayout) + 1024 (w cvt) + 16 (bucketize+sort)
    prep_kernel<<<5136, 256, 0, stream>>>(x, wblk, brows, bcols, xc, wb, bucket, bcnt);
    bsl_mfma_kernel<<<256, 512, 0, stream>>>(xc, wb, bucket, bcnt, out);
}